// Round 12
// baseline (239.674 us; speedup 1.0000x reference)
//
#include <hip/hip_runtime.h>
#include <math.h>

#define G 24
#define ROWS 577
#define HD 64
#define BH 96
#define EPSF 0.1f
#define COEFF 576.0f
#define BSHIFT 6.3543700408f  // log(575)

typedef float f32x4 __attribute__((ext_vector_type(4)));

// ---------------- K1: pure store-pattern probe (R11 skeleton, RPB=8, 4 passes) -----
#define RPB8 8
#define BPI8 ((ROWS + RPB8 - 1) / RPB8)  // 73
__global__ __launch_bounds__(256) void probe_span(float* __restrict__ out) {
    const int bh  = blockIdx.x / BPI8;
    const int blk = blockIdx.x - bh * BPI8;
    const int r0  = blk * RPB8;
    const int Ract = min(RPB8, ROWS - r0);
    const int tid = threadIdx.x;
    const size_t base = ((size_t)bh * ROWS + r0) * ROWS;

    for (int pass = 0; pass < 4; ++pass) {
        const float fp = (float)pass;
        // edges
        if (tid < 8 * RPB8) {
            const int rr = tid >> 3;
            const int s  = tid & 7;
            if (rr < Ract) {
                const size_t Sr = base + (size_t)rr * ROWS;
                const int phi = (int)((4 - ((Sr + 1) & 3)) & 3);
                const int F   = (576 - phi) >> 2;
                if (s == 0) out[Sr] = fp;
                else {
                    const int m = (s <= phi) ? (s - 1) : (4 * F + s - 1);
                    if (m < 576) out[Sr + 1 + m] = fp;
                }
            }
        }
        // main span
        {
            const int rr = tid >> 5;
            const int l  = tid & 31;
            if (rr < Ract) {
                const size_t Sr = base + (size_t)rr * ROWS;
                const int phi = (int)((4 - ((Sr + 1) & 3)) & 3);
                int m = phi + 4 * l;
                float* gp = out + Sr + 1 + m;
                #pragma unroll
                for (int it = 0; it < 5; ++it) {
                    if (m <= 572) {
                        f32x4 pk = { fp, fp + 1.f, fp, fp + 1.f };
                        __builtin_nontemporal_store(pk, (f32x4*)gp);
                    }
                    m  += 128;
                    gp += 128;
                }
            }
        }
    }
}

// ---------------- K2: light loop in situ (R11 phases 3+4, dummy params, 4 passes) --
__global__ __launch_bounds__(256) void probe_light(float* __restrict__ out) {
    const int bh  = blockIdx.x / BPI8;
    const int blk = blockIdx.x - bh * BPI8;
    const int r0  = blk * RPB8;
    const int Ract = min(RPB8, ROWS - r0);
    const int tid = threadIdx.x;

    __shared__ float s_ex0[RPB8][32];
    __shared__ float s_e1 [RPB8][32];

    for (int e = tid; e < RPB8 * 64; e += 256) {
        const int rr = e >> 6;
        const int k  = e & 63;
        const int rg = r0 + rr;
        const int n  = (rg > 0) ? rg - 1 : 0;
        const int in_ = (int)((unsigned)n / 24u);
        const int jn_ = n - in_ * 24;
        if (k < 25) {
            float v = 0.0f;
            if (k < 24) { const float t = (float)(in_ - k); v = expf(-0.05f * t * t); }
            s_ex0[rr][k] = v;
        } else if (k >= 32 && k < 60) {
            const int j  = k - 32;
            const int jm = (j >= 24) ? j - 24 : j;
            const float t = (float)(jn_ - jm);
            s_e1[rr][j] = expf(-0.07f * t * t);
        }
    }
    __syncthreads();

    const size_t base = ((size_t)bh * ROWS + r0) * ROWS;
    for (int pass = 0; pass < 4; ++pass) {
        const float fp = (float)pass;
        if (tid < 8 * RPB8) {
            const int rr = tid >> 3;
            const int s  = tid & 7;
            if (rr < Ract) {
                const size_t Sr = base + (size_t)rr * ROWS;
                const int phi = (int)((4 - ((Sr + 1) & 3)) & 3);
                const int F   = (576 - phi) >> 2;
                if (s == 0) out[Sr] = fp;
                else {
                    const int m = (s <= phi) ? (s - 1) : (4 * F + s - 1);
                    if (m < 576) {
                        const int im = (int)((unsigned)m / 24u);
                        const int jm = m - 24 * im;
                        out[Sr + 1 + m] = s_ex0[rr][im] * s_e1[rr][jm] + fp;
                    }
                }
            }
        }
        {
            const int rr = tid >> 5;
            const int l  = tid & 31;
            if (rr < Ract) {
                const size_t Sr = base + (size_t)rr * ROWS;
                const int phi = (int)((4 - ((Sr + 1) & 3)) & 3);
                int m  = phi + 4 * l;
                int im = (int)((unsigned)m / 24u);
                int jm = m - 24 * im;
                float* gp = out + Sr + 1 + m;
                const float* e0p = s_ex0[rr];
                const float* e1p = s_e1[rr];
                #pragma unroll
                for (int it = 0; it < 5; ++it) {
                    if (m <= 572) {
                        const float x0  = e0p[im];
                        const float x1  = e0p[im + 1];
                        const float e1a = e1p[jm],     e1b = e1p[jm + 1];
                        const float e1c = e1p[jm + 2], e1d = e1p[jm + 3];
                        f32x4 pk;
                        pk[0] = x0 * e1a + fp;
                        pk[1] = (jm >= 23 ? x1 : x0) * e1b + fp;
                        pk[2] = (jm >= 22 ? x1 : x0) * e1c + fp;
                        pk[3] = (jm >= 21 ? x1 : x0) * e1d + fp;
                        __builtin_nontemporal_store(pk, (f32x4*)gp);
                    }
                    m  += 128;
                    jm += 8;
                    const bool w = (jm >= 24);
                    im += w ? 6 : 5;
                    jm -= w ? 24 : 0;
                    gp += 128;
                }
            }
        }
    }
}

// ---------------- K3: real kernel, RPB=16 (prelude amortized 2x vs R11) ------------
#define RPB 16
#define BPI ((ROWS + RPB - 1) / RPB)  // 37
__global__ __launch_bounds__(256) void gaussian_augment_kernel(
    const float* __restrict__ q,
    const float* __restrict__ Wv,
    const float* __restrict__ bv,
    const float* __restrict__ Wa,
    const float* __restrict__ ba,
    float* __restrict__ out)
{
    const int bh  = blockIdx.x / BPI;
    const int blk = blockIdx.x - bh * BPI;
    const int r0  = blk * RPB;
    const int Ract = min(RPB, ROWS - r0);
    const int tid = threadIdx.x;

    __shared__ float s_dot[RPB][3];
    __shared__ float s_par[RPB][3];
    __shared__ float s_ex0[RPB][32];
    __shared__ float s_e1 [RPB][32];

    const int wave = tid >> 6;
    const int lane = tid & 63;
    #pragma unroll
    for (int pass = 0; pass < 4; ++pass) {
        const int rr = wave + 4 * pass;
        if (rr < Ract) {
            const int r = r0 + rr;
            const float* qrow = q + ((size_t)bh * ROWS + r) * HD;
            const float qv = qrow[lane];
            float p0 = qv * Wv[2 * lane + 0];
            float p1 = qv * Wv[2 * lane + 1];
            float p2 = qv * Wa[lane];
            #pragma unroll
            for (int off = 32; off >= 1; off >>= 1) {
                p0 += __shfl_xor(p0, off);
                p1 += __shfl_xor(p1, off);
                p2 += __shfl_xor(p2, off);
            }
            if (lane == 0) {
                s_dot[rr][0] = p0;
                s_dot[rr][1] = p1;
                s_dot[rr][2] = p2;
            }
        }
    }
    __syncthreads();

    if (tid < Ract) {
        const int r = r0 + tid;
        const float x0 = s_dot[tid][0] + bv[0] - BSHIFT;
        const float x1 = s_dot[tid][1] + bv[1] - BSHIFT;
        const float xa = s_dot[tid][2] + ba[0];
        const float var0 = COEFF / (1.0f + expf(-x0));
        const float var1 = COEFF / (1.0f + expf(-x1));
        s_par[tid][0] = 1.0f / (var0 + EPSF);
        s_par[tid][1] = 1.0f / (var1 + EPSF);
        const float alpha = fmaxf(xa, 0.0f) + log1pf(expf(-fabsf(xa)));
        s_par[tid][2] = (r == 0) ? 0.0f : alpha;
    }
    __syncthreads();

    for (int e = tid; e < RPB * 64; e += 256) {
        const int rr = e >> 6;
        const int k  = e & 63;
        if (rr < Ract) {
            const int rg = r0 + rr;
            const int n  = (rg > 0) ? rg - 1 : 0;
            const int in_ = (int)((unsigned)n / 24u);
            const int jn_ = n - in_ * 24;
            if (k < 25) {
                float v = 0.0f;
                if (k < 24) {
                    const float t = (float)(in_ - k);
                    v = s_par[rr][2] * expf(-0.5f * t * t * s_par[rr][0]);
                }
                s_ex0[rr][k] = v;
            } else if (k >= 32 && k < 60) {
                const int j  = k - 32;
                const int jm = (j >= 24) ? j - 24 : j;
                const float t = (float)(jn_ - jm);
                s_e1[rr][j] = expf(-0.5f * t * t * s_par[rr][1]);
            }
        }
    }
    __syncthreads();

    const size_t base = ((size_t)bh * ROWS + r0) * ROWS;

    if (tid < 8 * RPB) {
        const int rr = tid >> 3;
        const int s  = tid & 7;
        if (rr < Ract) {
            const size_t Sr = base + (size_t)rr * ROWS;
            const int phi = (int)((4 - ((Sr + 1) & 3)) & 3);
            const int F   = (576 - phi) >> 2;
            if (s == 0) out[Sr] = 0.0f;
            else {
                const int m = (s <= phi) ? (s - 1) : (4 * F + s - 1);
                if (m < 576) {
                    const int im = (int)((unsigned)m / 24u);
                    const int jm = m - 24 * im;
                    out[Sr + 1 + m] = s_ex0[rr][im] * s_e1[rr][jm];
                }
            }
        }
    }

    #pragma unroll
    for (int half = 0; half < 2; ++half) {
        const int rr = (tid >> 5) + 8 * half;
        const int l  = tid & 31;
        if (rr < Ract) {
            const size_t Sr = base + (size_t)rr * ROWS;
            const int phi = (int)((4 - ((Sr + 1) & 3)) & 3);
            int m  = phi + 4 * l;
            int im = (int)((unsigned)m / 24u);
            int jm = m - 24 * im;
            float* gp = out + Sr + 1 + m;
            const float* e0p = s_ex0[rr];
            const float* e1p = s_e1[rr];
            #pragma unroll
            for (int it = 0; it < 5; ++it) {
                if (m <= 572) {
                    const float x0  = e0p[im];
                    const float x1  = e0p[im + 1];
                    const float e1a = e1p[jm],     e1b = e1p[jm + 1];
                    const float e1c = e1p[jm + 2], e1d = e1p[jm + 3];
                    f32x4 pk;
                    pk[0] = x0 * e1a;
                    pk[1] = (jm >= 23 ? x1 : x0) * e1b;
                    pk[2] = (jm >= 22 ? x1 : x0) * e1c;
                    pk[3] = (jm >= 21 ? x1 : x0) * e1d;
                    __builtin_nontemporal_store(pk, (f32x4*)gp);
                }
                m  += 128;
                jm += 8;
                const bool w = (jm >= 24);
                im += w ? 6 : 5;
                jm -= w ? 24 : 0;
                gp += 128;
            }
        }
    }
}

extern "C" void kernel_launch(void* const* d_in, const int* in_sizes, int n_in,
                              void* d_out, int out_size, void* d_ws, size_t ws_size,
                              hipStream_t stream) {
    const float* q  = (const float*)d_in[0];
    const float* Wv = (const float*)d_in[1];
    const float* bv = (const float*)d_in[2];
    const float* Wa = (const float*)d_in[3];
    const float* ba = (const float*)d_in[4];
    float* out = (float*)d_out;

    // probes first — real kernel fully overwrites d_out
    probe_span <<<BH * BPI8, 256, 0, stream>>>(out);
    probe_light<<<BH * BPI8, 256, 0, stream>>>(out);
    gaussian_augment_kernel<<<BH * BPI, 256, 0, stream>>>(q, Wv, bv, Wa, ba, out);
}